// Round 6
// baseline (4527.200 us; speedup 1.0000x reference)
//
#include <hip/hip_runtime.h>
#include <hip/hip_bf16.h>
#include <math.h>

#define B 32
#define S 41
#define T 41
#define H 1024
#define V 16384
#define BH (B*H)

typedef unsigned int uint;
typedef unsigned short ushort;
typedef __attribute__((ext_vector_type(8))) short bf16x8;
typedef __attribute__((ext_vector_type(4))) float f32x4;
typedef _Float16 h2v __attribute__((ext_vector_type(2)));

__device__ __forceinline__ float fast_sigmoid(float x){ return 1.f/(1.f + __expf(-x)); }
__device__ __forceinline__ float fast_tanh(float x){
  float e = __expf(-2.f*fabsf(x));
  float r = (1.f - e)/(1.f + e);
  return copysignf(r, x);
}
__device__ __forceinline__ ushort f2h(float f){ return __builtin_bit_cast(unsigned short, (_Float16)f); }
__device__ __forceinline__ float h2f(ushort u){ return (float)__builtin_bit_cast(_Float16, u); }
__device__ __forceinline__ h2v bc2(uint u){ return __builtin_bit_cast(h2v, u); }
__device__ __forceinline__ ushort f2bf(float f){
  uint u = __float_as_uint(f);
  u = u + 0x7FFFu + ((u>>16)&1u);
  return (ushort)(u>>16);
}

#if defined(__has_builtin)
#if __has_builtin(__builtin_amdgcn_fdot2)
#define HAS_FDOT2 1
#endif
#endif
__device__ __forceinline__ float dot2(h2v a, h2v b, float c){
#ifdef HAS_FDOT2
  return __builtin_amdgcn_fdot2(a, b, c, false);
#else
  return fmaf((float)a.x, (float)b.x, fmaf((float)a.y, (float)b.y, c));
#endif
}

// ---------------- gather teacher-forced embeddings (f32): Xall[t*B+b][:] = emb[tok] ----------------
__global__ __launch_bounds__(256) void k_gather(const float* __restrict__ emb,
    const int* __restrict__ tgt, float* __restrict__ Xall){
  int r = blockIdx.x;            // 0..T*B-1
  int t = r / B, b = r % B;
  int tok = (t==0) ? 0 : tgt[b*T + (t-1)];
  const float4* src = (const float4*)(emb + (size_t)tok*H);
  float4* dst = (float4*)(Xall + (size_t)r*H);
  dst[threadIdx.x] = src[threadIdx.x];
}

__global__ __launch_bounds__(256) void k_bsum(const float* __restrict__ a,
                                              const float* __restrict__ b, float* __restrict__ o){
  int i = blockIdx.x*256 + threadIdx.x;
  o[i] = a[i] + b[i];
}

// ---------------- f32 -> f16 row-major convert ----------------
__global__ __launch_bounds__(256) void k_cvt16(const float* __restrict__ src,
                                               ushort* __restrict__ dst, int n8){
  int i = blockIdx.x*256 + threadIdx.x;
  if (i >= n8) return;
  const float4* s4 = (const float4*)src + (size_t)i*2;
  float4 a = s4[0], b = s4[1];
  union { ushort us[8]; uint4 v; } p;
  p.us[0]=f2h(a.x); p.us[1]=f2h(a.y); p.us[2]=f2h(a.z); p.us[3]=f2h(a.w);
  p.us[4]=f2h(b.x); p.us[5]=f2h(b.y); p.us[6]=f2h(b.z); p.us[7]=f2h(b.w);
  ((uint4*)dst)[i] = p.v;
}

// ---------------- Wc16T[kb][n][8] = f16 of ([Wq;Whh])[n][kb*8..+7] ----------------
__global__ __launch_bounds__(256) void k_cvt_wc(const float* __restrict__ Wq,
    const float* __restrict__ Whh, ushort* __restrict__ Wc16T){
  const int kb = blockIdx.x;                   // 0..127
  const int n  = blockIdx.y*256 + threadIdx.x; // 0..5119
  const float* src = (n < H) ? (Wq + (size_t)n*H + kb*8)
                             : (Whh + (size_t)(n-H)*H + kb*8);
  float4 a = *(const float4*)src;
  float4 b = *(const float4*)(src+4);
  union { ushort us[8]; uint4 v; } p;
  p.us[0]=f2h(a.x); p.us[1]=f2h(a.y); p.us[2]=f2h(a.z); p.us[3]=f2h(a.w);
  p.us[4]=f2h(b.x); p.us[5]=f2h(b.y); p.us[6]=f2h(b.z); p.us[7]=f2h(b.w);
  ((uint4*)Wc16T)[kb*5120 + n] = p.v;
}

// ---------------- bf16 MFMA GEMM: C[m][n] = sum_k A[m][k]*W[n*wstride+woff+k] (+bias) ----------------
// f32 inputs converted to bf16 during staging. K=1024. 128x128 tile, BK=32, 256 thr, 4 waves 2x2.
__global__ __launch_bounds__(256) void k_bgemm(const float* __restrict__ A,
    const float* __restrict__ W, const float* __restrict__ bias, float* __restrict__ C,
    int M, int N, int wstride, int woff)
{
  __shared__ ushort As[128*40];   // row stride 40 ushorts (80B): 32 data + 8 pad
  __shared__ ushort Bs[128*40];
  const int tid = threadIdx.x;
  const int n0 = blockIdx.x*128, m0 = blockIdx.y*128;
  const int row = tid>>1, half = tid&1;
  const int lane = tid & 63, widx = tid >> 6;
  const int wm = (widx>>1)*64, wn = (widx&1)*64;

  int arow = m0 + row; if (arow > M-1) arow = M-1;
  const float* ga = A + (size_t)arow*1024 + half*16;
  const float* gw = W + (size_t)(n0+row)*wstride + woff + half*16;
  ushort* sa = &As[row*40 + half*16];
  ushort* sb = &Bs[row*40 + half*16];

  f32x4 acc[4][4] = {};

  for (int k0 = 0; k0 < 1024; k0 += 32) {
    float4 a0 = *(const float4*)(ga+k0),   a1 = *(const float4*)(ga+k0+4);
    float4 a2 = *(const float4*)(ga+k0+8), a3 = *(const float4*)(ga+k0+12);
    float4 w0 = *(const float4*)(gw+k0),   w1 = *(const float4*)(gw+k0+4);
    float4 w2 = *(const float4*)(gw+k0+8), w3 = *(const float4*)(gw+k0+12);
    __syncthreads();
    {
      union { ushort us[8]; uint4 v; } p, q;
      p.us[0]=f2bf(a0.x); p.us[1]=f2bf(a0.y); p.us[2]=f2bf(a0.z); p.us[3]=f2bf(a0.w);
      p.us[4]=f2bf(a1.x); p.us[5]=f2bf(a1.y); p.us[6]=f2bf(a1.z); p.us[7]=f2bf(a1.w);
      q.us[0]=f2bf(a2.x); q.us[1]=f2bf(a2.y); q.us[2]=f2bf(a2.z); q.us[3]=f2bf(a2.w);
      q.us[4]=f2bf(a3.x); q.us[5]=f2bf(a3.y); q.us[6]=f2bf(a3.z); q.us[7]=f2bf(a3.w);
      *(uint4*)sa = p.v; *(uint4*)(sa+8) = q.v;
      p.us[0]=f2bf(w0.x); p.us[1]=f2bf(w0.y); p.us[2]=f2bf(w0.z); p.us[3]=f2bf(w0.w);
      p.us[4]=f2bf(w1.x); p.us[5]=f2bf(w1.y); p.us[6]=f2bf(w1.z); p.us[7]=f2bf(w1.w);
      q.us[0]=f2bf(w2.x); q.us[1]=f2bf(w2.y); q.us[2]=f2bf(w2.z); q.us[3]=f2bf(w2.w);
      q.us[4]=f2bf(w3.x); q.us[5]=f2bf(w3.y); q.us[6]=f2bf(w3.z); q.us[7]=f2bf(w3.w);
      *(uint4*)sb = p.v; *(uint4*)(sb+8) = q.v;
    }
    __syncthreads();
    bf16x8 af[4], bf[4];
    #pragma unroll
    for (int i=0;i<4;i++)
      af[i] = *(const bf16x8*)&As[(wm + i*16 + (lane&15))*40 + (lane>>4)*8];
    #pragma unroll
    for (int j=0;j<4;j++)
      bf[j] = *(const bf16x8*)&Bs[(wn + j*16 + (lane&15))*40 + (lane>>4)*8];
    #pragma unroll
    for (int i=0;i<4;i++)
      #pragma unroll
      for (int j=0;j<4;j++)
        acc[i][j] = __builtin_amdgcn_mfma_f32_16x16x32_bf16(af[i], bf[j], acc[i][j], 0, 0, 0);
  }

  #pragma unroll
  for (int i=0;i<4;i++){
    #pragma unroll
    for (int j=0;j<4;j++){
      int n = n0 + wn + j*16 + (lane&15);
      float bv = bias ? bias[n] : 0.f;
      #pragma unroll
      for (int qq=0;qq<4;qq++){
        int m = m0 + wm + i*16 + ((lane>>4)<<2) + qq;
        if (m < M) C[(size_t)m*N + n] = acc[i][j][qq] + bv;
      }
    }
  }
}

// ---------------- the 41-step recurrence: 32 self-contained blocks (one per batch) ----------------
__global__ __launch_bounds__(1024) void k_loop(
    const ushort* __restrict__ Wc16T,   // [128][5120][8] f16
    const float* __restrict__ bq,
    const ushort* __restrict__ keys16,  // [B*S][1024] f16
    const float* __restrict__ Vw, const float* __restrict__ bV,
    const float* __restrict__ GxF,      // [T*B][4096] f32
    const ushort* __restrict__ encW16,  // [B*S][4096] f16
    const float* __restrict__ ehid,     // [B][H]
    float* __restrict__ hhist,          // [B*T][H] f32
    float* __restrict__ attn_out,       // [B][T][S]
    float* __restrict__ hf, float* __restrict__ cf)
{
  __shared__ __align__(16) ushort h16_sh[H];
  __shared__ __align__(16) float q_sh[H];
  __shared__ __align__(16) float vw_sh[H];
  __shared__ float sc_sh[64];

  const int b = blockIdx.x;
  const int tid = threadIdx.x;
  const int lane = tid & 63, wv = tid >> 6;

  h16_sh[tid] = f2h(ehid[b*H + tid]);
  if (tid < 256) *(float4*)&vw_sh[tid*4] = ((const float4*)Vw)[tid];
  const float bqr = bq[tid];
  const float bV0 = bV[0];
  float creg = 0.f;
  __syncthreads();

  const uint4* wc = (const uint4*)Wc16T;

  for (int t = 0; t < T; ++t) {
    // ---- P1: q[tid] and gh_{i,f,g,o}[tid] = dot(Wc rows, h) ----
    float qa = 0.f, g0 = 0.f, g1 = 0.f, g2 = 0.f, g3 = 0.f;
    {
      int idx = tid;
      #pragma unroll 2
      for (int kb = 0; kb < 128; ++kb) {
        uint4 hv = *(const uint4*)&h16_sh[kb*8];
        h2v h0 = bc2(hv.x), h1 = bc2(hv.y), h2_ = bc2(hv.z), h3 = bc2(hv.w);
        uint4 w0 = wc[idx];
        uint4 w1 = wc[idx + 1024];
        uint4 w2 = wc[idx + 2048];
        uint4 w3 = wc[idx + 3072];
        uint4 w4 = wc[idx + 4096];
        qa = dot2(bc2(w0.x),h0,qa); qa = dot2(bc2(w0.y),h1,qa); qa = dot2(bc2(w0.z),h2_,qa); qa = dot2(bc2(w0.w),h3,qa);
        g0 = dot2(bc2(w1.x),h0,g0); g0 = dot2(bc2(w1.y),h1,g0); g0 = dot2(bc2(w1.z),h2_,g0); g0 = dot2(bc2(w1.w),h3,g0);
        g1 = dot2(bc2(w2.x),h0,g1); g1 = dot2(bc2(w2.y),h1,g1); g1 = dot2(bc2(w2.z),h2_,g1); g1 = dot2(bc2(w2.w),h3,g1);
        g2 = dot2(bc2(w3.x),h0,g2); g2 = dot2(bc2(w3.y),h1,g2); g2 = dot2(bc2(w3.z),h2_,g2); g2 = dot2(bc2(w3.w),h3,g2);
        g3 = dot2(bc2(w4.x),h0,g3); g3 = dot2(bc2(w4.y),h1,g3); g3 = dot2(bc2(w4.z),h2_,g3); g3 = dot2(bc2(w4.w),h3,g3);
        idx += 5120;
      }
    }
    q_sh[tid] = qa + bqr;
    __syncthreads();

    // ---- P2: scores (16 waves over 41 s) ----
    for (int s = wv; s < S; s += 16) {
      const ushort* kr = keys16 + ((size_t)b*S + s)*H + lane*16;
      uint4 k0 = *(const uint4*)kr;
      uint4 k1 = *(const uint4*)(kr+8);
      const float* qp = q_sh + lane*16;
      const float* vp = vw_sh + lane*16;
      float part = 0.f;
      #define SC2(u, e) { h2v hh = bc2(u); \
        part += fast_tanh(qp[e] + (float)hh.x) * vp[e]; \
        part += fast_tanh(qp[e+1] + (float)hh.y) * vp[e+1]; }
      SC2(k0.x,0) SC2(k0.y,2) SC2(k0.z,4) SC2(k0.w,6)
      SC2(k1.x,8) SC2(k1.y,10) SC2(k1.z,12) SC2(k1.w,14)
      #undef SC2
      #pragma unroll
      for (int off=32; off>0; off>>=1) part += __shfl_xor(part, off);
      if (lane == 0) sc_sh[s] = part + bV0;
    }
    __syncthreads();

    // ---- P3: softmax over 41 (wave 0) ----
    if (tid < 64) {
      float val = (tid < S) ? sc_sh[tid] : -1e30f;
      float m = val;
      #pragma unroll
      for (int off=32; off>0; off>>=1) m = fmaxf(m, __shfl_xor(m, off));
      float e = (tid < S) ? __expf(val - m) : 0.f;
      float ssum = e;
      #pragma unroll
      for (int off=32; off>0; off>>=1) ssum += __shfl_xor(ssum, off);
      if (tid < S) {
        float w = e / ssum;
        sc_sh[tid] = w;
        attn_out[((size_t)b*T + t)*S + tid] = w;
      }
    }
    __syncthreads();

    // ---- P4: gates + LSTM (thread m = tid) ----
    {
      size_t gxb = ((size_t)t*B + b)*(4*H) + tid;
      float f0 = GxF[gxb]       + g0;
      float f1 = GxF[gxb + H]   + g1;
      float f2 = GxF[gxb + 2*H] + g2;
      float f3 = GxF[gxb + 3*H] + g3;
      const ushort* ep = encW16 + (size_t)b*S*(4*H) + tid;
      #pragma unroll 4
      for (int s = 0; s < S; ++s) {
        float w = sc_sh[s];
        const ushort* e4 = ep + (size_t)s*(4*H);
        f0 = fmaf(w, h2f(e4[0]),   f0);
        f1 = fmaf(w, h2f(e4[H]),   f1);
        f2 = fmaf(w, h2f(e4[2*H]), f2);
        f3 = fmaf(w, h2f(e4[3*H]), f3);
      }
      float ig = fast_sigmoid(f0);
      float fg = fast_sigmoid(f1);
      float gg = fast_tanh(f2);
      float og = fast_sigmoid(f3);
      creg = fg*creg + ig*gg;
      float hn = og * fast_tanh(creg);
      h16_sh[tid] = f2h(hn);
      hhist[((size_t)b*T + t)*H + tid] = hn;
      if (t == T-1) { hf[b*H + tid] = hn; cf[b*H + tid] = creg; }
    }
    __syncthreads();
  }
}

// ---------------- log_softmax in-place over rows of 16384 ----------------
__global__ __launch_bounds__(256) void k_logsm(float* __restrict__ p_all)
{
  float* p = p_all + (size_t)blockIdx.x * V;
  const int tid = threadIdx.x;
  const int lane = tid & 63, wave = tid >> 6;
  __shared__ float red[4];
  float4 v[16];
  float m = -1e30f;
  #pragma unroll
  for (int j=0;j<16;j++){
    v[j] = *(const float4*)(p + 4*(tid + 256*j));
    m = fmaxf(m, fmaxf(fmaxf(v[j].x, v[j].y), fmaxf(v[j].z, v[j].w)));
  }
  #pragma unroll
  for (int off=32; off>0; off>>=1) m = fmaxf(m, __shfl_xor(m, off));
  if (lane==0) red[wave] = m;
  __syncthreads();
  m = fmaxf(fmaxf(red[0], red[1]), fmaxf(red[2], red[3]));
  float ssum = 0.f;
  #pragma unroll
  for (int j=0;j<16;j++){
    ssum += __expf(v[j].x - m) + __expf(v[j].y - m) + __expf(v[j].z - m) + __expf(v[j].w - m);
  }
  #pragma unroll
  for (int off=32; off>0; off>>=1) ssum += __shfl_xor(ssum, off);
  __syncthreads();
  if (lane==0) red[wave] = ssum;
  __syncthreads();
  float lse = m + __logf(red[0] + red[1] + red[2] + red[3]);
  #pragma unroll
  for (int j=0;j<16;j++){
    float4 o; o.x = v[j].x - lse; o.y = v[j].y - lse; o.z = v[j].z - lse; o.w = v[j].w - lse;
    *(float4*)(p + 4*(tid + 256*j)) = o;
  }
}

extern "C" void kernel_launch(void* const* d_in, const int* in_sizes, int n_in,
                              void* d_out, int out_size, void* d_ws, size_t ws_size,
                              hipStream_t stream) {
  const float* enc   = (const float*)d_in[0];
  const float* ehid  = (const float*)d_in[1];
  const int*   tgt   = (const int*)  d_in[2];
  const float* emb   = (const float*)d_in[3];
  const float* Wq    = (const float*)d_in[4];
  const float* bq    = (const float*)d_in[5];
  const float* Wk    = (const float*)d_in[6];
  const float* bk    = (const float*)d_in[7];
  const float* Vw    = (const float*)d_in[8];
  const float* bV    = (const float*)d_in[9];
  const float* Wih   = (const float*)d_in[10];
  const float* Whh   = (const float*)d_in[11];
  const float* bih   = (const float*)d_in[12];
  const float* bhh   = (const float*)d_in[13];
  const float* Wout  = (const float*)d_in[14];
  const float* bout  = (const float*)d_in[15];

  float* out  = (float*)d_out;
  float* dec  = out;                          // [1312][16384] = 21,495,808 f32
  float* hf   = out + (size_t)B*T*V;
  float* cf   = hf + BH;
  float* attn = cf + BH;

  // scratch inside dec (all dead before the logits GEMM rewrites dec)
  float*  Xall   = dec;                       //  1,343,488 f32
  float*  keysF  = dec +  1343488;            //  1,343,488 f32
  float*  GxF    = dec +  2686976;            //  5,373,952 f32
  float*  encWF  = dec +  8060928;            //  5,373,952 f32
  ushort* keys16 = (ushort*)(dec + 13434880); //  1,343,488 f16 (671,744 slots)
  ushort* encW16 = (ushort*)(dec + 14106624); //  5,373,952 f16 (2,686,976 slots)
  ushort* Wc16T  = (ushort*)(dec + 16793600); //  5,242,880 f16 (2,621,440 slots) -> ends 19,415,040

  float* ws = (float*)d_ws;
  float* hhist = ws;                          // 1,343,488 f32
  float* bsum  = ws + 1343488;                // 4096

  k_gather<<<T*B, 256, 0, stream>>>(emb, tgt, Xall);
  k_bsum<<<(4*H)/256, 256, 0, stream>>>(bih, bhh, bsum);

  // keys = enc @ Wk^T + bk
  { dim3 g(H/128, 11);     k_bgemm<<<g, 256, 0, stream>>>(enc,  Wk,  bk,     keysF, B*S, H,   H,   0); }
  // Gx = Xall @ Wih[:, :H]^T + (bih+bhh)
  { dim3 g((4*H)/128, 11); k_bgemm<<<g, 256, 0, stream>>>(Xall, Wih, bsum,   GxF,   T*B, 4*H, 2*H, 0); }
  // encW = enc @ Wih[:, H:]^T
  { dim3 g((4*H)/128, 11); k_bgemm<<<g, 256, 0, stream>>>(enc,  Wih, nullptr,encWF, B*S, 4*H, 2*H, H); }

  k_cvt16<<<(B*S*H/8 + 255)/256, 256, 0, stream>>>(keysF, keys16, B*S*H/8);
  k_cvt16<<<(B*S*4*H/8 + 255)/256, 256, 0, stream>>>(encWF, encW16, B*S*4*H/8);
  { dim3 g(128, 20); k_cvt_wc<<<g, 256, 0, stream>>>(Wq, Whh, Wc16T); }

  // the 41-step recurrence: 32 independent blocks, no cross-block sync
  k_loop<<<B, 1024, 0, stream>>>(Wc16T, bq, keys16, Vw, bV, GxF, encW16, ehid,
                                 hhist, attn, hf, cf);

  // logits = hhist @ Wout^T + bout -> dec rows (row = b*T+t), then log_softmax
  { dim3 g(V/128, 11);     k_bgemm<<<g, 256, 0, stream>>>(hhist, Wout, bout, dec, B*T, V, H, 0); }
  k_logsm<<<B*T, 256, 0, stream>>>(dec);
}

// Round 7
// 2078.729 us; speedup vs baseline: 2.1779x; 2.1779x over previous
//
#include <hip/hip_runtime.h>
#include <hip/hip_bf16.h>
#include <math.h>

#define B 32
#define S 41
#define T 41
#define H 1024
#define V 16384
#define BH (B*H)

typedef unsigned int uint;
typedef unsigned short ushort;
typedef __attribute__((ext_vector_type(8))) short bf16x8;
typedef __attribute__((ext_vector_type(4))) float f32x4;
typedef _Float16 h2v __attribute__((ext_vector_type(2)));

__device__ __forceinline__ float fast_sigmoid(float x){ return 1.f/(1.f + __expf(-x)); }
__device__ __forceinline__ float fast_tanh(float x){
  float e = __expf(-2.f*fabsf(x));
  float r = (1.f - e)/(1.f + e);
  return copysignf(r, x);
}
__device__ __forceinline__ ushort f2h(float f){ return __builtin_bit_cast(unsigned short, (_Float16)f); }
__device__ __forceinline__ float h2f(ushort u){ return (float)__builtin_bit_cast(_Float16, u); }
__device__ __forceinline__ h2v bc2(uint u){ return __builtin_bit_cast(h2v, u); }
__device__ __forceinline__ ushort f2bf(float f){
  uint u = __float_as_uint(f);
  u = u + 0x7FFFu + ((u>>16)&1u);
  return (ushort)(u>>16);
}

#if defined(__has_builtin)
#if __has_builtin(__builtin_amdgcn_fdot2)
#define HAS_FDOT2 1
#endif
#endif
__device__ __forceinline__ float dot2(h2v a, h2v b, float c){
#ifdef HAS_FDOT2
  return __builtin_amdgcn_fdot2(a, b, c, false);
#else
  return fmaf((float)a.x, (float)b.x, fmaf((float)a.y, (float)b.y, c));
#endif
}

// ---------------- 2-level device barrier (release/acquire via compiler fences) ----------------
// bar layout (uints): [g*32] sub-counters g=0..7 ; [256] root ; [288+g*32] go-flags
__device__ __forceinline__ void gbar(uint* bar, int phase){
  __syncthreads();                 // compiler drains vmcnt before s_barrier -> block stores in L2
  if (threadIdx.x == 0){
    const int gid = blockIdx.x >> 5;
    __builtin_amdgcn_fence(__ATOMIC_RELEASE, "agent");       // write back dirty L2 (cross-XCD visibility)
    uint old = __hip_atomic_fetch_add(&bar[gid*32], 1u, __ATOMIC_RELAXED, __HIP_MEMORY_SCOPE_AGENT);
    if ((old & 31u) == 31u){       // last block of this group of 32
      uint r = __hip_atomic_fetch_add(&bar[256], 1u, __ATOMIC_RELAXED, __HIP_MEMORY_SCOPE_AGENT);
      if ((r & 7u) == 7u){         // last group overall: broadcast go
        #pragma unroll
        for (int g = 0; g < 8; ++g)
          __hip_atomic_store(&bar[288+g*32], (uint)phase, __ATOMIC_RELAXED, __HIP_MEMORY_SCOPE_AGENT);
      }
    }
    while (__hip_atomic_load(&bar[288+gid*32], __ATOMIC_RELAXED, __HIP_MEMORY_SCOPE_AGENT) < (uint)phase)
      __builtin_amdgcn_s_sleep(2);
    __builtin_amdgcn_fence(__ATOMIC_ACQUIRE, "agent");       // invalidate L1/L2 -> read fresh
  }
  __syncthreads();
}

// ---------------- init: h16 = f16(encoder_hidden[0]); zero barrier ----------------
__global__ __launch_bounds__(256) void k_init(const float* __restrict__ eh,
                                              ushort* __restrict__ h16, uint* __restrict__ bar){
  int i = blockIdx.x*256 + threadIdx.x;
  h16[i] = f2h(eh[i]);
  if (i < 1024) bar[i] = 0;
}

__global__ __launch_bounds__(256) void k_bsum(const float* __restrict__ a,
                                              const float* __restrict__ b, float* __restrict__ o){
  int i = blockIdx.x*256 + threadIdx.x;
  o[i] = a[i] + b[i];
}

__global__ __launch_bounds__(256) void k_gather(const float* __restrict__ emb,
    const int* __restrict__ tgt, float* __restrict__ Xall){
  int r = blockIdx.x;
  int t = r / B, b = r % B;
  int tok = (t==0) ? 0 : tgt[b*T + (t-1)];
  const float4* src = (const float4*)(emb + (size_t)tok*H);
  float4* dst = (float4*)(Xall + (size_t)r*H);
  dst[threadIdx.x] = src[threadIdx.x];
}

// ---------------- f32 -> f16 row-major convert ----------------
__global__ __launch_bounds__(256) void k_cvt16(const float* __restrict__ src,
                                               ushort* __restrict__ dst, int n8){
  int i = blockIdx.x*256 + threadIdx.x;
  if (i >= n8) return;
  const float4* s4 = (const float4*)src + (size_t)i*2;
  float4 a = s4[0], b = s4[1];
  union { ushort us[8]; uint4 v; } p;
  p.us[0]=f2h(a.x); p.us[1]=f2h(a.y); p.us[2]=f2h(a.z); p.us[3]=f2h(a.w);
  p.us[4]=f2h(b.x); p.us[5]=f2h(b.y); p.us[6]=f2h(b.z); p.us[7]=f2h(b.w);
  ((uint4*)dst)[i] = p.v;
}

// ---------------- Wc16T[kb][n][8] = f16 of ([Wq;Whh])[n][kb*8..+7] ----------------
__global__ __launch_bounds__(256) void k_cvt_wc(const float* __restrict__ Wq,
    const float* __restrict__ Whh, ushort* __restrict__ Wc16T){
  const int kb = blockIdx.x;                   // 0..127
  const int n  = blockIdx.y*256 + threadIdx.x; // 0..5119
  const float* src = (n < H) ? (Wq + (size_t)n*H + kb*8)
                             : (Whh + (size_t)(n-H)*H + kb*8);
  float4 a = *(const float4*)src;
  float4 b = *(const float4*)(src+4);
  union { ushort us[8]; uint4 v; } p;
  p.us[0]=f2h(a.x); p.us[1]=f2h(a.y); p.us[2]=f2h(a.z); p.us[3]=f2h(a.w);
  p.us[4]=f2h(b.x); p.us[5]=f2h(b.y); p.us[6]=f2h(b.z); p.us[7]=f2h(b.w);
  ((uint4*)Wc16T)[kb*5120 + n] = p.v;
}

// ---------------- bf16 MFMA GEMM (same as R6) ----------------
__global__ __launch_bounds__(256) void k_bgemm(const float* __restrict__ A,
    const float* __restrict__ W, const float* __restrict__ bias, float* __restrict__ C,
    int M, int N, int wstride, int woff)
{
  __shared__ ushort As[128*40];
  __shared__ ushort Bs[128*40];
  const int tid = threadIdx.x;
  const int n0 = blockIdx.x*128, m0 = blockIdx.y*128;
  const int row = tid>>1, half = tid&1;
  const int lane = tid & 63, widx = tid >> 6;
  const int wm = (widx>>1)*64, wn = (widx&1)*64;

  int arow = m0 + row; if (arow > M-1) arow = M-1;
  const float* ga = A + (size_t)arow*1024 + half*16;
  const float* gw = W + (size_t)(n0+row)*wstride + woff + half*16;
  ushort* sa = &As[row*40 + half*16];
  ushort* sb = &Bs[row*40 + half*16];

  f32x4 acc[4][4] = {};

  for (int k0 = 0; k0 < 1024; k0 += 32) {
    float4 a0 = *(const float4*)(ga+k0),   a1 = *(const float4*)(ga+k0+4);
    float4 a2 = *(const float4*)(ga+k0+8), a3 = *(const float4*)(ga+k0+12);
    float4 w0 = *(const float4*)(gw+k0),   w1 = *(const float4*)(gw+k0+4);
    float4 w2 = *(const float4*)(gw+k0+8), w3 = *(const float4*)(gw+k0+12);
    __syncthreads();
    {
      union { ushort us[8]; uint4 v; } p, q;
      p.us[0]=f2bf(a0.x); p.us[1]=f2bf(a0.y); p.us[2]=f2bf(a0.z); p.us[3]=f2bf(a0.w);
      p.us[4]=f2bf(a1.x); p.us[5]=f2bf(a1.y); p.us[6]=f2bf(a1.z); p.us[7]=f2bf(a1.w);
      q.us[0]=f2bf(a2.x); q.us[1]=f2bf(a2.y); q.us[2]=f2bf(a2.z); q.us[3]=f2bf(a2.w);
      q.us[4]=f2bf(a3.x); q.us[5]=f2bf(a3.y); q.us[6]=f2bf(a3.z); q.us[7]=f2bf(a3.w);
      *(uint4*)sa = p.v; *(uint4*)(sa+8) = q.v;
      p.us[0]=f2bf(w0.x); p.us[1]=f2bf(w0.y); p.us[2]=f2bf(w0.z); p.us[3]=f2bf(w0.w);
      p.us[4]=f2bf(w1.x); p.us[5]=f2bf(w1.y); p.us[6]=f2bf(w1.z); p.us[7]=f2bf(w1.w);
      q.us[0]=f2bf(w2.x); q.us[1]=f2bf(w2.y); q.us[2]=f2bf(w2.z); q.us[3]=f2bf(w2.w);
      q.us[4]=f2bf(w3.x); q.us[5]=f2bf(w3.y); q.us[6]=f2bf(w3.z); q.us[7]=f2bf(w3.w);
      *(uint4*)sb = p.v; *(uint4*)(sb+8) = q.v;
    }
    __syncthreads();
    bf16x8 af[4], bf[4];
    #pragma unroll
    for (int i=0;i<4;i++)
      af[i] = *(const bf16x8*)&As[(wm + i*16 + (lane&15))*40 + (lane>>4)*8];
    #pragma unroll
    for (int j=0;j<4;j++)
      bf[j] = *(const bf16x8*)&Bs[(wn + j*16 + (lane&15))*40 + (lane>>4)*8];
    #pragma unroll
    for (int i=0;i<4;i++)
      #pragma unroll
      for (int j=0;j<4;j++)
        acc[i][j] = __builtin_amdgcn_mfma_f32_16x16x32_bf16(af[i], bf[j], acc[i][j], 0, 0, 0);
  }

  #pragma unroll
  for (int i=0;i<4;i++){
    #pragma unroll
    for (int j=0;j<4;j++){
      int n = n0 + wn + j*16 + (lane&15);
      float bv = bias ? bias[n] : 0.f;
      #pragma unroll
      for (int qq=0;qq<4;qq++){
        int m = m0 + wm + i*16 + ((lane>>4)<<2) + qq;
        if (m < M) C[(size_t)m*N + n] = acc[i][j][qq] + bv;
      }
    }
  }
}

// ---------------- persistent loop: 256 blocks, 2 barriers/step ----------------
// PA (blocks 0..159): rows n in [bid*32, bid*32+32) of [q|gh] = [Wq;Whh] @ h, all 32 batches.
// PB (all 256 = (b, mc)): redundant scores+softmax; gates slice m in [mc*128,+128); LSTM (c in regs).
__global__ __launch_bounds__(512) void k_loop(
    const ushort* __restrict__ Wc16T,   // [128][5120][8] f16
    const float* __restrict__ bq,
    const ushort* __restrict__ keys16,  // [B*S][1024] f16
    const float* __restrict__ Vw, const float* __restrict__ bV,
    const float* __restrict__ GxF,      // [T*B][4096] f32
    const ushort* __restrict__ encW16,  // [B*S][4096] f16
    float* __restrict__ qg,             // [B][H] f32
    float* __restrict__ ghg,            // [B][4H] f32
    ushort* __restrict__ h16,           // [B][H] f16
    float* __restrict__ hhist,          // [B*T][H] f32
    float* __restrict__ attn_out,       // [B][T][S]
    float* __restrict__ hf, float* __restrict__ cf,
    uint* __restrict__ bar)
{
  __shared__ __align__(16) uint4 h4s[128*33];      // PA: h in LDS [kb][b] padded; PB aliases q
  float* qs = (float*)h4s;                          // PB: q[b] staged (4KB)
  __shared__ __align__(16) float vw_sh[H];
  __shared__ float sc_sh[64];
  __shared__ float ga[512];

  const int tid = threadIdx.x;
  const int bid = blockIdx.x;
  const int pb_b = bid >> 3, pb_mc = bid & 7;
  const bool pa_on = (bid < 160);

  if (tid < 256) *(float4*)&vw_sh[tid*4] = ((const float4*)Vw)[tid];

  // PA thread mapping: r = row-in-slice, bh = batch-pair index
  const int r = tid & 31, bh = tid >> 5;
  const int pa_n = bid*32 + r;
  const int b0 = bh*2, b1 = bh*2 + 1;
  const uint4* wrow = (const uint4*)Wc16T + pa_n;
  const float bqv = (pa_n < H) ? bq[pa_n] : 0.f;

  // PB gate mapping
  const int g = tid >> 7, mm = tid & 127;
  const int gn = g*H + pb_mc*128 + mm;

  float creg = 0.f;
  const float bV0 = bV[0];

  for (int t = 0; t < T; ++t) {
    // ================= PA =================
    if (pa_on) {
      // stage h (all 32 batches, f16) into LDS [kb][b], kb-major global reads (coalesced)
      const uint4* hv = (const uint4*)h16;
      #pragma unroll
      for (int pass = 0; pass < 8; ++pass) {
        int unit = pass*512 + tid;              // b = unit>>7, kb = unit&127
        int ub = unit >> 7, ukb = unit & 127;
        h4s[ukb*33 + ub] = hv[ub*128 + ukb];
      }
      __syncthreads();
      float acc0 = 0.f, acc1 = 0.f;
      #pragma unroll 4
      for (int kb = 0; kb < 128; ++kb) {
        uint4 w  = wrow[(size_t)kb*5120];
        uint4 ha = h4s[kb*33 + b0];
        uint4 hb = h4s[kb*33 + b1];
        acc0 = dot2(bc2(w.x), bc2(ha.x), acc0);
        acc0 = dot2(bc2(w.y), bc2(ha.y), acc0);
        acc0 = dot2(bc2(w.z), bc2(ha.z), acc0);
        acc0 = dot2(bc2(w.w), bc2(ha.w), acc0);
        acc1 = dot2(bc2(w.x), bc2(hb.x), acc1);
        acc1 = dot2(bc2(w.y), bc2(hb.y), acc1);
        acc1 = dot2(bc2(w.z), bc2(hb.z), acc1);
        acc1 = dot2(bc2(w.w), bc2(hb.w), acc1);
      }
      if (pa_n < H) {
        qg[b0*H + pa_n] = acc0 + bqv;
        qg[b1*H + pa_n] = acc1 + bqv;
      } else {
        ghg[(size_t)b0*4*H + (pa_n - H)] = acc0;
        ghg[(size_t)b1*4*H + (pa_n - H)] = acc1;
      }
    }
    gbar(bar, 2*t + 1);

    // ================= PB =================
    {
      if (tid < 256) ((float4*)qs)[tid] = ((const float4*)(qg + pb_b*H))[tid];
      float ghv = ghg[(size_t)pb_b*4*H + gn];
      __syncthreads();
      // scores: 8 waves over 41 s (redundant across the 8 mc-blocks of batch b)
      {
        const int lane = tid & 63, wv = tid >> 6;
        for (int s = wv; s < S; s += 8) {
          const ushort* kr = keys16 + ((size_t)pb_b*S + s)*H + lane*16;
          uint4 k0 = *(const uint4*)kr;
          uint4 k1 = *(const uint4*)(kr + 8);
          const float* qp = qs + lane*16;
          const float* vp = vw_sh + lane*16;
          float part = 0.f;
          #define SC2(u, e) { h2v hh = bc2(u); \
            part += fast_tanh(qp[e]   + (float)hh.x) * vp[e]; \
            part += fast_tanh(qp[e+1] + (float)hh.y) * vp[e+1]; }
          SC2(k0.x,0) SC2(k0.y,2) SC2(k0.z,4) SC2(k0.w,6)
          SC2(k1.x,8) SC2(k1.y,10) SC2(k1.z,12) SC2(k1.w,14)
          #undef SC2
          #pragma unroll
          for (int off = 32; off > 0; off >>= 1) part += __shfl_xor(part, off);
          if (lane == 0) sc_sh[s] = part + bV0;
        }
      }
      __syncthreads();
      if (tid < 64) {
        float val = (tid < S) ? sc_sh[tid] : -1e30f;
        float m = val;
        #pragma unroll
        for (int off = 32; off > 0; off >>= 1) m = fmaxf(m, __shfl_xor(m, off));
        float e = (tid < S) ? __expf(val - m) : 0.f;
        float ssum = e;
        #pragma unroll
        for (int off = 32; off > 0; off >>= 1) ssum += __shfl_xor(ssum, off);
        if (tid < S) {
          float w = e / ssum;
          sc_sh[tid] = w;
          if (pb_mc == 0) attn_out[((size_t)pb_b*T + t)*S + tid] = w;
        }
      }
      __syncthreads();
      // gates slice
      {
        float acc = GxF[((size_t)t*B + pb_b)*4*H + gn] + ghv;
        const ushort* ep = encW16 + (size_t)pb_b*S*4*H + gn;
        #pragma unroll 4
        for (int s = 0; s < S; ++s)
          acc = fmaf(sc_sh[s], h2f(ep[(size_t)s*4*H]), acc);
        ga[g*128 + mm] = acc;
      }
      __syncthreads();
      if (tid < 128) {
        float ig = fast_sigmoid(ga[tid]);
        float fg = fast_sigmoid(ga[128+tid]);
        float gg = fast_tanh   (ga[256+tid]);
        float og = fast_sigmoid(ga[384+tid]);
        creg = fg*creg + ig*gg;
        float hn = og * fast_tanh(creg);
        int m = pb_mc*128 + tid;
        h16[pb_b*H + m] = f2h(hn);
        hhist[((size_t)pb_b*T + t)*H + m] = hn;
        if (t == T-1) { hf[pb_b*H + m] = hn; cf[pb_b*H + m] = creg; }
      }
    }
    gbar(bar, 2*t + 2);
  }
}

// ---------------- log_softmax in-place over rows of 16384 ----------------
__global__ __launch_bounds__(256) void k_logsm(float* __restrict__ p_all)
{
  float* p = p_all + (size_t)blockIdx.x * V;
  const int tid = threadIdx.x;
  const int lane = tid & 63, wave = tid >> 6;
  __shared__ float red[4];
  float4 v[16];
  float m = -1e30f;
  #pragma unroll
  for (int j=0;j<16;j++){
    v[j] = *(const float4*)(p + 4*(tid + 256*j));
    m = fmaxf(m, fmaxf(fmaxf(v[j].x, v[j].y), fmaxf(v[j].z, v[j].w)));
  }
  #pragma unroll
  for (int off=32; off>0; off>>=1) m = fmaxf(m, __shfl_xor(m, off));
  if (lane==0) red[wave] = m;
  __syncthreads();
  m = fmaxf(fmaxf(red[0], red[1]), fmaxf(red[2], red[3]));
  float ssum = 0.f;
  #pragma unroll
  for (int j=0;j<16;j++){
    ssum += __expf(v[j].x - m) + __expf(v[j].y - m) + __expf(v[j].z - m) + __expf(v[j].w - m);
  }
  #pragma unroll
  for (int off=32; off>0; off>>=1) ssum += __shfl_xor(ssum, off);
  __syncthreads();
  if (lane==0) red[wave] = ssum;
  __syncthreads();
  float lse = m + __logf(red[0] + red[1] + red[2] + red[3]);
  #pragma unroll
  for (int j=0;j<16;j++){
    float4 o; o.x = v[j].x - lse; o.y = v[j].y - lse; o.z = v[j].z - lse; o.w = v[j].w - lse;
    *(float4*)(p + 4*(tid + 256*j)) = o;
  }
}

extern "C" void kernel_launch(void* const* d_in, const int* in_sizes, int n_in,
                              void* d_out, int out_size, void* d_ws, size_t ws_size,
                              hipStream_t stream) {
  const float* enc   = (const float*)d_in[0];
  const float* ehid  = (const float*)d_in[1];
  const int*   tgt   = (const int*)  d_in[2];
  const float* emb   = (const float*)d_in[3];
  const float* Wq    = (const float*)d_in[4];
  const float* bq    = (const float*)d_in[5];
  const float* Wk    = (const float*)d_in[6];
  const float* bk    = (const float*)d_in[7];
  const float* Vw    = (const float*)d_in[8];
  const float* bV    = (const float*)d_in[9];
  const float* Wih   = (const float*)d_in[10];
  const float* Whh   = (const float*)d_in[11];
  const float* bih   = (const float*)d_in[12];
  const float* bhh   = (const float*)d_in[13];
  const float* Wout  = (const float*)d_in[14];
  const float* bout  = (const float*)d_in[15];

  float* out  = (float*)d_out;
  float* dec  = out;                          // [1312][16384] = 21,495,808 f32
  float* hf   = out + (size_t)B*T*V;
  float* cf   = hf + BH;
  float* attn = cf + BH;

  // scratch inside dec (all dead before the logits GEMM rewrites dec)
  float*  Xall   = dec;                       //  1,343,488 f32
  float*  keysF  = dec +  1343488;            //  1,343,488 f32
  float*  GxF    = dec +  2686976;            //  5,373,952 f32
  float*  encWF  = dec +  8060928;            //  5,373,952 f32
  ushort* keys16 = (ushort*)(dec + 13434880); //  671,744 f32-slots
  ushort* encW16 = (ushort*)(dec + 14106624); //  2,686,976 f32-slots
  ushort* Wc16T  = (ushort*)(dec + 16793600); //  2,621,440 f32-slots -> ends 19,415,040

  float* ws = (float*)d_ws;
  float*  hhist = ws;                          // 1,343,488 f32
  float*  bsum  = ws + 1343488;                // 4,096
  ushort* h16   = (ushort*)(ws + 1347584);     // 32,768 f16 (16,384 slots)
  float*  qg    = ws + 1363968;                // 32,768
  float*  ghg   = ws + 1396736;                // 131,072
  uint*   bar   = (uint*)(ws + 1527808);       // 1,024 uints

  k_init<<<BH/256, 256, 0, stream>>>(ehid, h16, bar);
  k_bsum<<<(4*H)/256, 256, 0, stream>>>(bih, bhh, bsum);
  k_gather<<<T*B, 256, 0, stream>>>(emb, tgt, Xall);

  // keys = enc @ Wk^T + bk
  { dim3 g(H/128, 11);     k_bgemm<<<g, 256, 0, stream>>>(enc,  Wk,  bk,     keysF, B*S, H,   H,   0); }
  // Gx = Xall @ Wih[:, :H]^T + (bih+bhh)
  { dim3 g((4*H)/128, 11); k_bgemm<<<g, 256, 0, stream>>>(Xall, Wih, bsum,   GxF,   T*B, 4*H, 2*H, 0); }
  // encW = enc @ Wih[:, H:]^T
  { dim3 g((4*H)/128, 11); k_bgemm<<<g, 256, 0, stream>>>(enc,  Wih, nullptr,encWF, B*S, 4*H, 2*H, H); }

  k_cvt16<<<(B*S*H/8 + 255)/256, 256, 0, stream>>>(keysF, keys16, B*S*H/8);
  k_cvt16<<<(B*S*4*H/8 + 255)/256, 256, 0, stream>>>(encWF, encW16, B*S*4*H/8);
  { dim3 g(128, 20); k_cvt_wc<<<g, 256, 0, stream>>>(Wq, Whh, Wc16T); }

  // the 41-step recurrence: 256 persistent blocks, 2 device barriers per step
  k_loop<<<256, 512, 0, stream>>>(Wc16T, bq, keys16, Vw, bV, GxF, encW16,
                                  qg, ghg, h16, hhist, attn, hf, cf, bar);

  // logits = hhist @ Wout^T + bout -> dec rows (row = b*T+t), then log_softmax
  { dim3 g(V/128, 11);     k_bgemm<<<g, 256, 0, stream>>>(hhist, Wout, bout, dec, B*T, V, H, 0); }
  k_logsm<<<B*T, 256, 0, stream>>>(dec);
}

// Round 8
// 1661.767 us; speedup vs baseline: 2.7243x; 1.2509x over previous
//
#include <hip/hip_runtime.h>
#include <hip/hip_bf16.h>
#include <math.h>

#define B 32
#define S 41
#define T 41
#define H 1024
#define V 16384
#define BH (B*H)
#define NBLK 256
#define NTHR 512
#define RPB 20   // weight rows per block: 256*20 = 5120

typedef unsigned int uint;
typedef unsigned short ushort;
typedef __attribute__((ext_vector_type(8))) short bf16x8;
typedef __attribute__((ext_vector_type(4))) float f32x4;
typedef _Float16 h2v __attribute__((ext_vector_type(2)));

__device__ __forceinline__ float fast_sigmoid(float x){ return 1.f/(1.f + __expf(-x)); }
__device__ __forceinline__ float fast_tanh(float x){
  float e = __expf(-2.f*fabsf(x));
  float r = (1.f - e)/(1.f + e);
  return copysignf(r, x);
}
__device__ __forceinline__ ushort f2h(float f){ return __builtin_bit_cast(unsigned short, (_Float16)f); }
__device__ __forceinline__ float h2f(ushort u){ return (float)__builtin_bit_cast(_Float16, u); }
__device__ __forceinline__ h2v bc2(uint u){ return __builtin_bit_cast(h2v, u); }
__device__ __forceinline__ ushort f2bf(float f){
  uint u = __float_as_uint(f);
  u = u + 0x7FFFu + ((u>>16)&1u);
  return (ushort)(u>>16);
}

#if defined(__has_builtin)
#if __has_builtin(__builtin_amdgcn_fdot2)
#define HAS_FDOT2 1
#endif
#endif
__device__ __forceinline__ float dot2(h2v a, h2v b, float c){
#ifdef HAS_FDOT2
  return __builtin_amdgcn_fdot2(a, b, c, false);
#else
  return fmaf((float)a.x, (float)b.x, fmaf((float)a.y, (float)b.y, c));
#endif
}

// ---- coherence-point (L1+L2-bypassing) LOADS for cross-block state ----
__device__ __forceinline__ float ld_sc_f32(const float* p){
  float r;
  asm volatile("global_load_dword %0, %1, off sc0 sc1\n\ts_waitcnt vmcnt(0)"
               : "=v"(r) : "v"(p) : "memory");
  return r;
}
__device__ __forceinline__ float4 ld_sc_f128(const float4* p){
  float4 r;
  asm volatile("global_load_dwordx4 %0, %1, off sc0 sc1\n\ts_waitcnt vmcnt(0)"
               : "=v"(r) : "v"(p) : "memory");
  return r;
}
__device__ __forceinline__ void ldx8_sc(const uint* p, uint4* r){
  asm volatile(
    "global_load_dwordx4 %0, %8, off sc0 sc1\n\t"
    "global_load_dwordx4 %1, %8, off offset:16 sc0 sc1\n\t"
    "global_load_dwordx4 %2, %8, off offset:32 sc0 sc1\n\t"
    "global_load_dwordx4 %3, %8, off offset:48 sc0 sc1\n\t"
    "global_load_dwordx4 %4, %8, off offset:64 sc0 sc1\n\t"
    "global_load_dwordx4 %5, %8, off offset:80 sc0 sc1\n\t"
    "global_load_dwordx4 %6, %8, off offset:96 sc0 sc1\n\t"
    "global_load_dwordx4 %7, %8, off offset:112 sc0 sc1\n\t"
    "s_waitcnt vmcnt(0)"
    : "=&v"(r[0]), "=&v"(r[1]), "=&v"(r[2]), "=&v"(r[3]),
      "=&v"(r[4]), "=&v"(r[5]), "=&v"(r[6]), "=&v"(r[7])
    : "v"(p) : "memory");
}

// ---- 2-level device barrier: release fence (wbl2) on arrival, NO acquire fence.
// Consumers read cross-block state via sc0sc1 loads (coherence point) instead.
__device__ __forceinline__ void gbar(uint* bar, int phase){
  __syncthreads();   // compiler drains vmcnt before s_barrier -> all waves' stores in L2
  if (threadIdx.x == 0){
    const int gid = blockIdx.x >> 5;
    __builtin_amdgcn_fence(__ATOMIC_RELEASE, "agent");  // wbl2: dirty L2 -> coherence point
    uint old = __hip_atomic_fetch_add(&bar[gid*32], 1u, __ATOMIC_RELAXED, __HIP_MEMORY_SCOPE_AGENT);
    if ((old & 31u) == 31u){
      uint r = __hip_atomic_fetch_add(&bar[256], 1u, __ATOMIC_RELAXED, __HIP_MEMORY_SCOPE_AGENT);
      if ((r & 7u) == 7u){
        #pragma unroll
        for (int g = 0; g < 8; ++g)
          __hip_atomic_store(&bar[288+g*32], (uint)phase, __ATOMIC_RELAXED, __HIP_MEMORY_SCOPE_AGENT);
      }
    }
    while (__hip_atomic_load(&bar[288+gid*32], __ATOMIC_RELAXED, __HIP_MEMORY_SCOPE_AGENT) < (uint)phase)
      __builtin_amdgcn_s_sleep(2);
  }
  __syncthreads();
}

// ---------------- init: h16 = f16(encoder_hidden[0]); zero barrier ----------------
__global__ __launch_bounds__(256) void k_init(const float* __restrict__ eh,
                                              ushort* __restrict__ h16, uint* __restrict__ bar){
  int i = blockIdx.x*256 + threadIdx.x;
  h16[i] = f2h(eh[i]);
  if (i < 1024) bar[i] = 0;
}

__global__ __launch_bounds__(256) void k_bsum(const float* __restrict__ a,
                                              const float* __restrict__ b, float* __restrict__ o){
  int i = blockIdx.x*256 + threadIdx.x;
  o[i] = a[i] + b[i];
}

__global__ __launch_bounds__(256) void k_gather(const float* __restrict__ emb,
    const int* __restrict__ tgt, float* __restrict__ Xall){
  int r = blockIdx.x;
  int t = r / B, b = r % B;
  int tok = (t==0) ? 0 : tgt[b*T + (t-1)];
  const float4* src = (const float4*)(emb + (size_t)tok*H);
  float4* dst = (float4*)(Xall + (size_t)r*H);
  dst[threadIdx.x] = src[threadIdx.x];
}

// ---------------- f32 -> f16 row-major convert ----------------
__global__ __launch_bounds__(256) void k_cvt16(const float* __restrict__ src,
                                               ushort* __restrict__ dst, int n8){
  int i = blockIdx.x*256 + threadIdx.x;
  if (i >= n8) return;
  const float4* s4 = (const float4*)src + (size_t)i*2;
  float4 a = s4[0], b = s4[1];
  union { ushort us[8]; uint4 v; } p;
  p.us[0]=f2h(a.x); p.us[1]=f2h(a.y); p.us[2]=f2h(a.z); p.us[3]=f2h(a.w);
  p.us[4]=f2h(b.x); p.us[5]=f2h(b.y); p.us[6]=f2h(b.z); p.us[7]=f2h(b.w);
  ((uint4*)dst)[i] = p.v;
}

// ---------------- bf16 MFMA GEMM (unchanged, R6/R7-proven) ----------------
__global__ __launch_bounds__(256) void k_bgemm(const float* __restrict__ A,
    const float* __restrict__ W, const float* __restrict__ bias, float* __restrict__ C,
    int M, int N, int wstride, int woff)
{
  __shared__ ushort As[128*40];
  __shared__ ushort Bs[128*40];
  const int tid = threadIdx.x;
  const int n0 = blockIdx.x*128, m0 = blockIdx.y*128;
  const int row = tid>>1, half = tid&1;
  const int lane = tid & 63, widx = tid >> 6;
  const int wm = (widx>>1)*64, wn = (widx&1)*64;

  int arow = m0 + row; if (arow > M-1) arow = M-1;
  const float* ga = A + (size_t)arow*1024 + half*16;
  const float* gw = W + (size_t)(n0+row)*wstride + woff + half*16;
  ushort* sa = &As[row*40 + half*16];
  ushort* sb = &Bs[row*40 + half*16];

  f32x4 acc[4][4] = {};

  for (int k0 = 0; k0 < 1024; k0 += 32) {
    float4 a0 = *(const float4*)(ga+k0),   a1 = *(const float4*)(ga+k0+4);
    float4 a2 = *(const float4*)(ga+k0+8), a3 = *(const float4*)(ga+k0+12);
    float4 w0 = *(const float4*)(gw+k0),   w1 = *(const float4*)(gw+k0+4);
    float4 w2 = *(const float4*)(gw+k0+8), w3 = *(const float4*)(gw+k0+12);
    __syncthreads();
    {
      union { ushort us[8]; uint4 v; } p, q;
      p.us[0]=f2bf(a0.x); p.us[1]=f2bf(a0.y); p.us[2]=f2bf(a0.z); p.us[3]=f2bf(a0.w);
      p.us[4]=f2bf(a1.x); p.us[5]=f2bf(a1.y); p.us[6]=f2bf(a1.z); p.us[7]=f2bf(a1.w);
      q.us[0]=f2bf(a2.x); q.us[1]=f2bf(a2.y); q.us[2]=f2bf(a2.z); q.us[3]=f2bf(a2.w);
      q.us[4]=f2bf(a3.x); q.us[5]=f2bf(a3.y); q.us[6]=f2bf(a3.z); q.us[7]=f2bf(a3.w);
      *(uint4*)sa = p.v; *(uint4*)(sa+8) = q.v;
      p.us[0]=f2bf(w0.x); p.us[1]=f2bf(w0.y); p.us[2]=f2bf(w0.z); p.us[3]=f2bf(w0.w);
      p.us[4]=f2bf(w1.x); p.us[5]=f2bf(w1.y); p.us[6]=f2bf(w1.z); p.us[7]=f2bf(w1.w);
      q.us[0]=f2bf(w2.x); q.us[1]=f2bf(w2.y); q.us[2]=f2bf(w2.z); q.us[3]=f2bf(w2.w);
      q.us[4]=f2bf(w3.x); q.us[5]=f2bf(w3.y); q.us[6]=f2bf(w3.z); q.us[7]=f2bf(w3.w);
      *(uint4*)sb = p.v; *(uint4*)(sb+8) = q.v;
    }
    __syncthreads();
    bf16x8 af[4], bf[4];
    #pragma unroll
    for (int i=0;i<4;i++)
      af[i] = *(const bf16x8*)&As[(wm + i*16 + (lane&15))*40 + (lane>>4)*8];
    #pragma unroll
    for (int j=0;j<4;j++)
      bf[j] = *(const bf16x8*)&Bs[(wn + j*16 + (lane&15))*40 + (lane>>4)*8];
    #pragma unroll
    for (int i=0;i<4;i++)
      #pragma unroll
      for (int j=0;j<4;j++)
        acc[i][j] = __builtin_amdgcn_mfma_f32_16x16x32_bf16(af[i], bf[j], acc[i][j], 0, 0, 0);
  }

  #pragma unroll
  for (int i=0;i<4;i++){
    #pragma unroll
    for (int j=0;j<4;j++){
      int n = n0 + wn + j*16 + (lane&15);
      float bv = bias ? bias[n] : 0.f;
      #pragma unroll
      for (int qq=0;qq<4;qq++){
        int m = m0 + wm + i*16 + ((lane>>4)<<2) + qq;
        if (m < M) C[(size_t)m*N + n] = acc[i][j][qq] + bv;
      }
    }
  }
}

// ---------------- persistent loop: 256 blocks x 512 thr, LDS-resident weights ----------------
// PA: block owns weight rows [bid*20, +20); thread (b,ks) holds h-slice (64 f16) in regs,
//     computes 20 partials from LDS weights, LDS-reduce over ks, store q/gh (normal stores).
// PB: block=(b,mc): redundant scores from L2-warm keys; softmax; gates from LDS encW-T; LSTM.
__global__ __launch_bounds__(512) void k_loop(
    const ushort* __restrict__ Wc16,    // [5120][1024] f16 row-major
    const float* __restrict__ bq,
    const ushort* __restrict__ keys16,  // [B*S][1024] f16
    const float* __restrict__ Vw, const float* __restrict__ bV,
    const float* __restrict__ GxF,      // [T*B][4096] f32
    const ushort* __restrict__ encW16,  // [B*S][4096] f16
    float* __restrict__ qg,             // [B][H] f32
    float* __restrict__ ghg,            // [B][4H] f32
    ushort* __restrict__ h16,           // [B][H] f16
    float* __restrict__ hhist,          // [B*T][H] f32
    float* __restrict__ attn_out,       // [B][T][S]
    float* __restrict__ hf, float* __restrict__ cf,
    uint* __restrict__ bar)
{
  __shared__ __align__(16) uint   w_lds[RPB*516];   // 41,280 B: rows padded to 516 uints
  __shared__ __align__(16) ushort ew_lds[512*42];   // 43,008 B: encW-T [n_local][s] pad 42
  __shared__ __align__(16) float  red[RPB*512];     // 40,960 B: [r][ks][b]
  __shared__ __align__(16) float  q_sh[1024];       // 4 KB
  __shared__ __align__(16) float  vw_sh[1024];      // 4 KB
  __shared__ float sc_sh[64];
  __shared__ float ga[512];

  const int tid = threadIdx.x;
  const int bid = blockIdx.x;
  const int pb_b = bid >> 3, pb_mc = bid & 7;
  const int lane = tid & 63, wv = tid >> 6;

  // PA mapping
  const int pa_b = tid & 31, pa_ks = tid >> 5;      // batch, k-slice (16 slices of 64)
  // PB gate mapping: n_local = tid; global gate row index:
  const int gn = (tid >> 7)*H + pb_mc*128 + (tid & 127);

  // out-mapping (reduction consumers), static per thread
  const int oa = tid;            // oid round 0: r=oa>>5 in [0,16), b=oa&31
  const int ob_ = 512 + tid;     // oid round 1 (tid<128): r in [16,20)
  const int na = bid*RPB + (oa>>5);
  const int nb = bid*RPB + (ob_>>5);
  const float bqa = (na < H) ? bq[na] : 0.f;
  const float bqb = (tid < 128 && nb < H) ? bq[nb] : 0.f;

  // ---- one-time staging: weights slice, encW-T slice, Vw ----
  for (int i = tid; i < RPB*128; i += NTHR){        // 2560 uint4
    int r = i >> 7, j = i & 127;
    uint4 v = *((const uint4*)(Wc16 + (size_t)(bid*RPB + r)*1024) + j);
    *(uint4*)&w_lds[r*516 + j*4] = v;
  }
  for (int s = 0; s < S; ++s)
    ew_lds[tid*42 + s] = encW16[((size_t)pb_b*S + s)*4096 + gn];
  if (tid < 256) *(float4*)&vw_sh[tid*4] = ((const float4*)Vw)[tid];
  const float bV0 = bV[0];
  float creg = 0.f;
  __syncthreads();

  for (int t = 0; t < T; ++t) {
    // ================= PA =================
    {
      uint4 hr[8];
      ldx8_sc((const uint*)h16 + pa_b*512 + pa_ks*32, hr);
      float part[RPB];
      #pragma unroll
      for (int r = 0; r < RPB; ++r){
        const uint* wr = &w_lds[r*516 + pa_ks*32];
        float a0 = 0.f, a1 = 0.f;
        #pragma unroll
        for (int j = 0; j < 8; ++j){
          uint4 w = *(const uint4*)(wr + j*4);
          uint4 h = hr[j];
          a0 = dot2(bc2(w.x), bc2(h.x), a0);
          a1 = dot2(bc2(w.y), bc2(h.y), a1);
          a0 = dot2(bc2(w.z), bc2(h.z), a0);
          a1 = dot2(bc2(w.w), bc2(h.w), a1);
        }
        part[r] = a0 + a1;
      }
      #pragma unroll
      for (int r = 0; r < RPB; ++r) red[r*512 + pa_ks*32 + pa_b] = part[r];
      __syncthreads();
      // reduce over ks and store q/gh
      {
        int r = oa >> 5, b2 = oa & 31;
        const float* rp = &red[r*512 + b2];
        float s = 0.f;
        #pragma unroll
        for (int k2 = 0; k2 < 16; ++k2) s += rp[k2*32];
        if (na < H) qg[b2*H + na] = s + bqa;
        else        ghg[(size_t)b2*4*H + (na - H)] = s;
      }
      if (tid < 128){
        int r = ob_ >> 5, b2 = ob_ & 31;
        const float* rp = &red[r*512 + b2];
        float s = 0.f;
        #pragma unroll
        for (int k2 = 0; k2 < 16; ++k2) s += rp[k2*32];
        if (nb < H) qg[b2*H + nb] = s + bqb;
        else        ghg[(size_t)b2*4*H + (nb - H)] = s;
      }
    }
    gbar(bar, 2*t + 1);

    // ================= PB =================
    {
      if (tid < 256)
        *(float4*)&q_sh[tid*4] = ld_sc_f128((const float4*)(qg + pb_b*H) + tid);
      float ghv = ld_sc_f32(ghg + (size_t)pb_b*4*H + gn);
      __syncthreads();
      // scores: 8 waves over 41 s, keys from (L2-warm) global
      for (int s = wv; s < S; s += 8) {
        const ushort* kr = keys16 + ((size_t)pb_b*S + s)*H + lane*16;
        uint4 k0 = *(const uint4*)kr;
        uint4 k1 = *(const uint4*)(kr + 8);
        const float* qp = q_sh + lane*16;
        const float* vp = vw_sh + lane*16;
        float part = 0.f;
        #define SC2(u, e) { h2v hh = bc2(u); \
          part += fast_tanh(qp[e]   + (float)hh.x) * vp[e]; \
          part += fast_tanh(qp[e+1] + (float)hh.y) * vp[e+1]; }
        SC2(k0.x,0) SC2(k0.y,2) SC2(k0.z,4) SC2(k0.w,6)
        SC2(k1.x,8) SC2(k1.y,10) SC2(k1.z,12) SC2(k1.w,14)
        #undef SC2
        #pragma unroll
        for (int off = 32; off > 0; off >>= 1) part += __shfl_xor(part, off);
        if (lane == 0) sc_sh[s] = part + bV0;
      }
      __syncthreads();
      if (tid < 64) {
        float val = (tid < S) ? sc_sh[tid] : -1e30f;
        float m = val;
        #pragma unroll
        for (int off = 32; off > 0; off >>= 1) m = fmaxf(m, __shfl_xor(m, off));
        float e = (tid < S) ? __expf(val - m) : 0.f;
        float ssum = e;
        #pragma unroll
        for (int off = 32; off > 0; off >>= 1) ssum += __shfl_xor(ssum, off);
        if (tid < S) {
          float w = e / ssum;
          sc_sh[tid] = w;
          if (pb_mc == 0) attn_out[((size_t)pb_b*T + t)*S + tid] = w;
        }
      }
      __syncthreads();
      // gates: Gx (nt) + gh (sc) + sum_s w_s * encW (LDS)
      {
        float acc = __builtin_nontemporal_load(&GxF[((size_t)t*B + pb_b)*4*H + gn]) + ghv;
        const ushort* ep = &ew_lds[tid*42];
        #pragma unroll
        for (int s = 0; s < S; ++s)
          acc = fmaf(sc_sh[s], h2f(ep[s]), acc);
        ga[tid] = acc;
      }
      __syncthreads();
      if (tid < 128) {
        float ig = fast_sigmoid(ga[tid]);
        float fg = fast_sigmoid(ga[128+tid]);
        float gg = fast_tanh   (ga[256+tid]);
        float og = fast_sigmoid(ga[384+tid]);
        creg = fg*creg + ig*gg;
        float hn = og * fast_tanh(creg);
        int m = pb_mc*128 + tid;
        h16[pb_b*H + m] = f2h(hn);
        __builtin_nontemporal_store(hn, &hhist[((size_t)pb_b*T + t)*H + m]);
        if (t == T-1) { hf[pb_b*H + m] = hn; cf[pb_b*H + m] = creg; }
      }
    }
    gbar(bar, 2*t + 2);
  }
}

// ---------------- log_softmax in-place over rows of 16384 ----------------
__global__ __launch_bounds__(256) void k_logsm(float* __restrict__ p_all)
{
  float* p = p_all + (size_t)blockIdx.x * V;
  const int tid = threadIdx.x;
  const int lane = tid & 63, wave = tid >> 6;
  __shared__ float red[4];
  float4 v[16];
  float m = -1e30f;
  #pragma unroll
  for (int j=0;j<16;j++){
    v[j] = *(const float4*)(p + 4*(tid + 256*j));
    m = fmaxf(m, fmaxf(fmaxf(v[j].x, v[j].y), fmaxf(v[j].z, v[j].w)));
  }
  #pragma unroll
  for (int off=32; off>0; off>>=1) m = fmaxf(m, __shfl_xor(m, off));
  if (lane==0) red[wave] = m;
  __syncthreads();
  m = fmaxf(fmaxf(red[0], red[1]), fmaxf(red[2], red[3]));
  float ssum = 0.f;
  #pragma unroll
  for (int j=0;j<16;j++){
    ssum += __expf(v[j].x - m) + __expf(v[j].y - m) + __expf(v[j].z - m) + __expf(v[j].w - m);
  }
  #pragma unroll
  for (int off=32; off>0; off>>=1) ssum += __shfl_xor(ssum, off);
  __syncthreads();
  if (lane==0) red[wave] = ssum;
  __syncthreads();
  float lse = m + __logf(red[0] + red[1] + red[2] + red[3]);
  #pragma unroll
  for (int j=0;j<16;j++){
    float4 o; o.x = v[j].x - lse; o.y = v[j].y - lse; o.z = v[j].z - lse; o.w = v[j].w - lse;
    *(float4*)(p + 4*(tid + 256*j)) = o;
  }
}

extern "C" void kernel_launch(void* const* d_in, const int* in_sizes, int n_in,
                              void* d_out, int out_size, void* d_ws, size_t ws_size,
                              hipStream_t stream) {
  const float* enc   = (const float*)d_in[0];
  const float* ehid  = (const float*)d_in[1];
  const int*   tgt   = (const int*)  d_in[2];
  const float* emb   = (const float*)d_in[3];
  const float* Wq    = (const float*)d_in[4];
  const float* bq    = (const float*)d_in[5];
  const float* Wk    = (const float*)d_in[6];
  const float* bk    = (const float*)d_in[7];
  const float* Vw    = (const float*)d_in[8];
  const float* bV    = (const float*)d_in[9];
  const float* Wih   = (const float*)d_in[10];
  const float* Whh   = (const float*)d_in[11];
  const float* bih   = (const float*)d_in[12];
  const float* bhh   = (const float*)d_in[13];
  const float* Wout  = (const float*)d_in[14];
  const float* bout  = (const float*)d_in[15];

  float* out  = (float*)d_out;
  float* dec  = out;                          // [1312][16384] = 21,495,808 f32
  float* hf   = out + (size_t)B*T*V;
  float* cf   = hf + BH;
  float* attn = cf + BH;

  // scratch inside dec (all dead before the logits GEMM rewrites dec)
  float*  Xall   = dec;                       //  1,343,488 f32
  float*  keysF  = dec +  1343488;            //  1,343,488 f32
  float*  GxF    = dec +  2686976;            //  5,373,952 f32
  float*  encWF  = dec +  8060928;            //  5,373,952 f32
  ushort* keys16 = (ushort*)(dec + 13434880); //  671,744 f32-slots
  ushort* encW16 = (ushort*)(dec + 14106624); //  2,686,976 f32-slots
  ushort* Wc16   = (ushort*)(dec + 16793600); //  [5120][1024] f16, 2,621,440 f32-slots -> ends 19,415,040

  float* ws = (float*)d_ws;
  float*  hhist = ws;                          // 1,343,488 f32
  float*  bsum  = ws + 1343488;                // 4,096
  ushort* h16   = (ushort*)(ws + 1347584);     // 32,768 f16 (16,384 f32-slots)
  float*  qg    = ws + 1363968;                // 32,768
  float*  ghg   = ws + 1396736;                // 131,072
  uint*   bar   = (uint*)(ws + 1527808);       // 1,024 uints

  k_init<<<BH/256, 256, 0, stream>>>(ehid, h16, bar);
  k_bsum<<<(4*H)/256, 256, 0, stream>>>(bih, bhh, bsum);
  k_gather<<<T*B, 256, 0, stream>>>(emb, tgt, Xall);

  // keys = enc @ Wk^T + bk
  { dim3 g(H/128, 11);     k_bgemm<<<g, 256, 0, stream>>>(enc,  Wk,  bk,     keysF, B*S, H,   H,   0); }
  // Gx = Xall @ Wih[:, :H]^T + (bih+bhh)
  { dim3 g((4*H)/128, 11); k_bgemm<<<g, 256, 0, stream>>>(Xall, Wih, bsum,   GxF,   T*B, 4*H, 2*H, 0); }
  // encW = enc @ Wih[:, H:]^T
  { dim3 g((4*H)/128, 11); k_bgemm<<<g, 256, 0, stream>>>(enc,  Wih, nullptr,encWF, B*S, 4*H, 2*H, H); }

  k_cvt16<<<(B*S*H/8 + 255)/256, 256, 0, stream>>>(keysF, keys16, B*S*H/8);
  k_cvt16<<<(B*S*4*H/8 + 255)/256, 256, 0, stream>>>(encWF, encW16, B*S*4*H/8);
  // Wc16 = [Wq ; Whh] row-major f16
  k_cvt16<<<(H*H/8 + 255)/256, 256, 0, stream>>>(Wq,  Wc16,             H*H/8);
  k_cvt16<<<(4*H*H/8 + 255)/256, 256, 0, stream>>>(Whh, Wc16 + (size_t)H*H, 4*H*H/8);

  // the 41-step recurrence: 256 persistent blocks, release-only barriers
  {
    void* kargs[] = {
      (void*)&Wc16, (void*)&bq, (void*)&keys16, (void*)&Vw, (void*)&bV,
      (void*)&GxF, (void*)&encW16, (void*)&qg, (void*)&ghg,
      (void*)&h16, (void*)&hhist, (void*)&attn, (void*)&hf, (void*)&cf, (void*)&bar
    };
    hipLaunchCooperativeKernel((const void*)k_loop, dim3(NBLK), dim3(NTHR), kargs, 0, stream);
  }

  // logits = hhist @ Wout^T + bout -> dec rows (row = b*T+t), then log_softmax
  { dim3 g(V/128, 11);     k_bgemm<<<g, 256, 0, stream>>>(hhist, Wout, bout, dec, B*T, V, H, 0); }
  k_logsm<<<B*T, 256, 0, stream>>>(dec);
}

// Round 9
// 1282.642 us; speedup vs baseline: 3.5296x; 1.2956x over previous
//
#include <hip/hip_runtime.h>
#include <hip/hip_bf16.h>
#include <math.h>

#define B 32
#define S 41
#define T 41
#define H 1024
#define V 16384
#define BH (B*H)
#define NBLK 256
#define NTHR 512
#define RPB 20   // weight rows per block: 256*20 = 5120

typedef unsigned int uint;
typedef unsigned short ushort;
typedef __attribute__((ext_vector_type(8))) short bf16x8;
typedef __attribute__((ext_vector_type(4))) float f32x4;
typedef _Float16 h2v __attribute__((ext_vector_type(2)));

__device__ __forceinline__ float fast_sigmoid(float x){ return 1.f/(1.f + __expf(-x)); }
__device__ __forceinline__ float fast_tanh(float x){
  float e = __expf(-2.f*fabsf(x));
  float r = (1.f - e)/(1.f + e);
  return copysignf(r, x);
}
__device__ __forceinline__ ushort f2h(float f){ return __builtin_bit_cast(unsigned short, (_Float16)f); }
__device__ __forceinline__ float h2f(ushort u){ return (float)__builtin_bit_cast(_Float16, u); }
__device__ __forceinline__ h2v bc2(uint u){ return __builtin_bit_cast(h2v, u); }
__device__ __forceinline__ ushort f2bf(float f){
  uint u = __float_as_uint(f);
  u = u + 0x7FFFu + ((u>>16)&1u);
  return (ushort)(u>>16);
}

#if defined(__has_builtin)
#if __has_builtin(__builtin_amdgcn_fdot2)
#define HAS_FDOT2 1
#endif
#endif
__device__ __forceinline__ float dot2(h2v a, h2v b, float c){
#ifdef HAS_FDOT2
  return __builtin_amdgcn_fdot2(a, b, c, false);
#else
  return fmaf((float)a.x, (float)b.x, fmaf((float)a.y, (float)b.y, c));
#endif
}

// ---- coherence-point (cache-bypassing) accesses for cross-block state ----
__device__ __forceinline__ void ldx8_sc(const uint* p, uint4* r){
  asm volatile(
    "global_load_dwordx4 %0, %8, off sc0 sc1\n\t"
    "global_load_dwordx4 %1, %8, off offset:16 sc0 sc1\n\t"
    "global_load_dwordx4 %2, %8, off offset:32 sc0 sc1\n\t"
    "global_load_dwordx4 %3, %8, off offset:48 sc0 sc1\n\t"
    "global_load_dwordx4 %4, %8, off offset:64 sc0 sc1\n\t"
    "global_load_dwordx4 %5, %8, off offset:80 sc0 sc1\n\t"
    "global_load_dwordx4 %6, %8, off offset:96 sc0 sc1\n\t"
    "global_load_dwordx4 %7, %8, off offset:112 sc0 sc1\n\t"
    "s_waitcnt vmcnt(0)"
    : "=&v"(r[0]), "=&v"(r[1]), "=&v"(r[2]), "=&v"(r[3]),
      "=&v"(r[4]), "=&v"(r[5]), "=&v"(r[6]), "=&v"(r[7])
    : "v"(p) : "memory");
}
// q-slice (4x float4) + gh scalar, one wait
__device__ __forceinline__ void ld_qgh_sc(const float* qp, const float* gp,
                                          float4* q, float* gh){
  asm volatile(
    "global_load_dwordx4 %0, %5, off sc0 sc1\n\t"
    "global_load_dwordx4 %1, %5, off offset:16 sc0 sc1\n\t"
    "global_load_dwordx4 %2, %5, off offset:32 sc0 sc1\n\t"
    "global_load_dwordx4 %3, %5, off offset:48 sc0 sc1\n\t"
    "global_load_dword  %4, %6, off sc0 sc1\n\t"
    "s_waitcnt vmcnt(0)"
    : "=&v"(q[0]), "=&v"(q[1]), "=&v"(q[2]), "=&v"(q[3]), "=&v"(*gh)
    : "v"(qp), "v"(gp) : "memory");
}
__device__ __forceinline__ void st_sc_f32(float* p, float v){
  asm volatile("global_store_dword %0, %1, off sc0 sc1" :: "v"(p), "v"(v) : "memory");
}

// ---- full barrier (R8-proven): every block release-fences (wbl2) ----
__device__ __forceinline__ void gbar_full(uint* bar, int phase){
  asm volatile("s_waitcnt vmcnt(0)" ::: "memory");
  __syncthreads();
  if (threadIdx.x == 0){
    const int gid = blockIdx.x >> 5;
    __builtin_amdgcn_fence(__ATOMIC_RELEASE, "agent");
    uint old = __hip_atomic_fetch_add(&bar[gid*32], 1u, __ATOMIC_RELAXED, __HIP_MEMORY_SCOPE_AGENT);
    if ((old & 31u) == 31u){
      uint r = __hip_atomic_fetch_add(&bar[256], 1u, __ATOMIC_RELAXED, __HIP_MEMORY_SCOPE_AGENT);
      if ((r & 7u) == 7u){
        #pragma unroll
        for (int g = 0; g < 8; ++g)
          __hip_atomic_store(&bar[288+g*32], (uint)phase, __ATOMIC_RELAXED, __HIP_MEMORY_SCOPE_AGENT);
      }
    }
    while (__hip_atomic_load(&bar[288+gid*32], __ATOMIC_RELAXED, __HIP_MEMORY_SCOPE_AGENT) < (uint)phase)
      __builtin_amdgcn_s_sleep(2);
  }
  __syncthreads();
}

// ---- XCD-leader barrier: only the last block on each XCD fences (8 wbl2 total) ----
// slots: arrive bar[512+x*16], root bar[640], go bar[704+x*16], reg bar[832+x*16]
__device__ __forceinline__ void gbar_x(uint* bar, int phase,
                                       uint my_xcd, uint my_cnt, uint nx, uint lb){
  asm volatile("s_waitcnt vmcnt(0)" ::: "memory");
  __syncthreads();
  if (threadIdx.x == 0){
    uint old = __hip_atomic_fetch_add(&bar[512 + my_xcd*16], 1u, __ATOMIC_RELAXED, __HIP_MEMORY_SCOPE_AGENT);
    if (old == lb*my_cnt + (my_cnt - 1u)){        // last block of this XCD
      __builtin_amdgcn_fence(__ATOMIC_RELEASE, "agent");   // one wbl2 per XCD
      uint r = __hip_atomic_fetch_add(&bar[640], 1u, __ATOMIC_RELAXED, __HIP_MEMORY_SCOPE_AGENT);
      if (r == lb*nx + (nx - 1u)){                // last XCD overall
        #pragma unroll
        for (int g = 0; g < 8; ++g)
          __hip_atomic_store(&bar[704+g*16], (uint)phase, __ATOMIC_RELAXED, __HIP_MEMORY_SCOPE_AGENT);
      }
    }
    while (__hip_atomic_load(&bar[704+my_xcd*16], __ATOMIC_RELAXED, __HIP_MEMORY_SCOPE_AGENT) < (uint)phase)
      __builtin_amdgcn_s_sleep(2);
  }
  __syncthreads();
}

// ---------------- init: h16 = f16(encoder_hidden[0]); zero barrier ----------------
__global__ __launch_bounds__(256) void k_init(const float* __restrict__ eh,
                                              ushort* __restrict__ h16, uint* __restrict__ bar){
  int i = blockIdx.x*256 + threadIdx.x;
  h16[i] = f2h(eh[i]);
  if (i < 1024) bar[i] = 0;
}

__global__ __launch_bounds__(256) void k_bsum(const float* __restrict__ a,
                                              const float* __restrict__ b, float* __restrict__ o){
  int i = blockIdx.x*256 + threadIdx.x;
  o[i] = a[i] + b[i];
}

__global__ __launch_bounds__(256) void k_gather(const float* __restrict__ emb,
    const int* __restrict__ tgt, float* __restrict__ Xall){
  int r = blockIdx.x;
  int t = r / B, b = r % B;
  int tok = (t==0) ? 0 : tgt[b*T + (t-1)];
  const float4* src = (const float4*)(emb + (size_t)tok*H);
  float4* dst = (float4*)(Xall + (size_t)r*H);
  dst[threadIdx.x] = src[threadIdx.x];
}

// ---------------- f32 -> f16 row-major convert ----------------
__global__ __launch_bounds__(256) void k_cvt16(const float* __restrict__ src,
                                               ushort* __restrict__ dst, int n8){
  int i = blockIdx.x*256 + threadIdx.x;
  if (i >= n8) return;
  const float4* s4 = (const float4*)src + (size_t)i*2;
  float4 a = s4[0], b = s4[1];
  union { ushort us[8]; uint4 v; } p;
  p.us[0]=f2h(a.x); p.us[1]=f2h(a.y); p.us[2]=f2h(a.z); p.us[3]=f2h(a.w);
  p.us[4]=f2h(b.x); p.us[5]=f2h(b.y); p.us[6]=f2h(b.z); p.us[7]=f2h(b.w);
  ((uint4*)dst)[i] = p.v;
}

// ---------------- bf16 MFMA GEMM (R6-proven) ----------------
__global__ __launch_bounds__(256) void k_bgemm(const float* __restrict__ A,
    const float* __restrict__ W, const float* __restrict__ bias, float* __restrict__ C,
    int M, int N, int wstride, int woff)
{
  __shared__ ushort As[128*40];
  __shared__ ushort Bs[128*40];
  const int tid = threadIdx.x;
  const int n0 = blockIdx.x*128, m0 = blockIdx.y*128;
  const int row = tid>>1, half = tid&1;
  const int lane = tid & 63, widx = tid >> 6;
  const int wm = (widx>>1)*64, wn = (widx&1)*64;

  int arow = m0 + row; if (arow > M-1) arow = M-1;
  const float* ga = A + (size_t)arow*1024 + half*16;
  const float* gw = W + (size_t)(n0+row)*wstride + woff + half*16;
  ushort* sa = &As[row*40 + half*16];
  ushort* sb = &Bs[row*40 + half*16];

  f32x4 acc[4][4] = {};

  for (int k0 = 0; k0 < 1024; k0 += 32) {
    float4 a0 = *(const float4*)(ga+k0),   a1 = *(const float4*)(ga+k0+4);
    float4 a2 = *(const float4*)(ga+k0+8), a3 = *(const float4*)(ga+k0+12);
    float4 w0 = *(const float4*)(gw+k0),   w1 = *(const float4*)(gw+k0+4);
    float4 w2 = *(const float4*)(gw+k0+8), w3 = *(const float4*)(gw+k0+12);
    __syncthreads();
    {
      union { ushort us[8]; uint4 v; } p, q;
      p.us[0]=f2bf(a0.x); p.us[1]=f2bf(a0.y); p.us[2]=f2bf(a0.z); p.us[3]=f2bf(a0.w);
      p.us[4]=f2bf(a1.x); p.us[5]=f2bf(a1.y); p.us[6]=f2bf(a1.z); p.us[7]=f2bf(a1.w);
      q.us[0]=f2bf(a2.x); q.us[1]=f2bf(a2.y); q.us[2]=f2bf(a2.z); q.us[3]=f2bf(a2.w);
      q.us[4]=f2bf(a3.x); q.us[5]=f2bf(a3.y); q.us[6]=f2bf(a3.z); q.us[7]=f2bf(a3.w);
      *(uint4*)sa = p.v; *(uint4*)(sa+8) = q.v;
      p.us[0]=f2bf(w0.x); p.us[1]=f2bf(w0.y); p.us[2]=f2bf(w0.z); p.us[3]=f2bf(w0.w);
      p.us[4]=f2bf(w1.x); p.us[5]=f2bf(w1.y); p.us[6]=f2bf(w1.z); p.us[7]=f2bf(w1.w);
      q.us[0]=f2bf(w2.x); q.us[1]=f2bf(w2.y); q.us[2]=f2bf(w2.z); q.us[3]=f2bf(w2.w);
      q.us[4]=f2bf(w3.x); q.us[5]=f2bf(w3.y); q.us[6]=f2bf(w3.z); q.us[7]=f2bf(w3.w);
      *(uint4*)sb = p.v; *(uint4*)(sb+8) = q.v;
    }
    __syncthreads();
    bf16x8 af[4], bf[4];
    #pragma unroll
    for (int i=0;i<4;i++)
      af[i] = *(const bf16x8*)&As[(wm + i*16 + (lane&15))*40 + (lane>>4)*8];
    #pragma unroll
    for (int j=0;j<4;j++)
      bf[j] = *(const bf16x8*)&Bs[(wn + j*16 + (lane&15))*40 + (lane>>4)*8];
    #pragma unroll
    for (int i=0;i<4;i++)
      #pragma unroll
      for (int j=0;j<4;j++)
        acc[i][j] = __builtin_amdgcn_mfma_f32_16x16x32_bf16(af[i], bf[j], acc[i][j], 0, 0, 0);
  }

  #pragma unroll
  for (int i=0;i<4;i++){
    #pragma unroll
    for (int j=0;j<4;j++){
      int n = n0 + wn + j*16 + (lane&15);
      float bv = bias ? bias[n] : 0.f;
      #pragma unroll
      for (int qq=0;qq<4;qq++){
        int m = m0 + wm + i*16 + ((lane>>4)<<2) + qq;
        if (m < M) C[(size_t)m*N + n] = acc[i][j][qq] + bv;
      }
    }
  }
}

// ---------------- persistent loop: 256 blocks x 512 thr ----------------
__global__ __launch_bounds__(512, 2) void k_loop(
    const ushort* __restrict__ Wc16,    // [5120][1024] f16 row-major
    const float* __restrict__ bq,
    const ushort* __restrict__ keys16,  // [B*S][1024] f16
    const float* __restrict__ Vw, const float* __restrict__ bV,
    const float* __restrict__ GxF,      // [T*B][4096] f32
    const ushort* __restrict__ encW16,  // [B*S][4096] f16
    float* __restrict__ qg,             // [B][H] f32
    float* __restrict__ ghg,            // [B][4H] f32
    ushort* __restrict__ h16,           // [B][H] f16
    float* __restrict__ hhist,          // [B*T][H] f32
    float* __restrict__ attn_out,       // [B][T][S]
    float* __restrict__ hf, float* __restrict__ cf,
    uint* __restrict__ bar)
{
  __shared__ __align__(16) uint   w_lds[RPB*516];   // 41,280 B
  __shared__ __align__(16) ushort ew_lds[512*42];   // 43,008 B
  __shared__ __align__(16) float  red[RPB*512];     // 40,960 B
  __shared__ float sc_sh[64];
  __shared__ float ga[512];

  const int tid = threadIdx.x;
  const int bid = blockIdx.x;
  const int pb_b = bid >> 3, pb_mc = bid & 7;
  const int lane = tid & 63, wv = tid >> 6;

  const int pa_b = tid & 31, pa_ks = tid >> 5;
  const int gn = (tid >> 7)*H + pb_mc*128 + (tid & 127);

  const int na = bid*RPB + (tid>>5);
  const int nb = bid*RPB + 16 + (tid>>5);
  const float bqa = (na < H) ? bq[na] : 0.f;
  const float bqb = (tid < 128 && nb < H) ? bq[nb] : 0.f;

  // barrier bookkeeping (meaningful in tid0 only)
  uint my_xcd = 0, my_cnt = 0, nx = 8, lb = 0;
  if (tid == 0){
    uint x;
    asm volatile("s_getreg_b32 %0, hwreg(20, 0, 32)" : "=s"(x));
    my_xcd = x & 7u;
    __hip_atomic_fetch_add(&bar[832 + my_xcd*16], 1u, __ATOMIC_RELAXED, __HIP_MEMORY_SCOPE_AGENT);
  }

  // ---- one-time staging ----
  for (int i = tid; i < RPB*128; i += NTHR){
    int r = i >> 7, j = i & 127;
    uint4 v = *((const uint4*)(Wc16 + (size_t)(bid*RPB + r)*1024) + j);
    *(uint4*)&w_lds[r*516 + j*4] = v;
  }
  for (int s = 0; s < S; ++s)
    ew_lds[tid*42 + s] = encW16[((size_t)pb_b*S + s)*4096 + gn];
  float vreg[16];
  {
    const float4* vp = (const float4*)(Vw + lane*16);
    *(float4*)&vreg[0] = vp[0]; *(float4*)&vreg[4]  = vp[1];
    *(float4*)&vreg[8] = vp[2]; *(float4*)&vreg[12] = vp[3];
  }
  const float bV0 = bV[0];
  float creg = 0.f;
  __syncthreads();

  for (int t = 0; t < T; ++t) {
    // ================= PA =================
    {
      uint4 hr[8];
      ldx8_sc((const uint*)h16 + pa_b*512 + pa_ks*32, hr);
      float part[RPB];
      #pragma unroll
      for (int r = 0; r < RPB; ++r){
        const uint* wr = &w_lds[r*516 + pa_ks*32];
        float a0 = 0.f, a1 = 0.f;
        #pragma unroll
        for (int j = 0; j < 8; ++j){
          uint4 w = *(const uint4*)(wr + j*4);
          uint4 h = hr[j];
          a0 = dot2(bc2(w.x), bc2(h.x), a0);
          a1 = dot2(bc2(w.y), bc2(h.y), a1);
          a0 = dot2(bc2(w.z), bc2(h.z), a0);
          a1 = dot2(bc2(w.w), bc2(h.w), a1);
        }
        part[r] = a0 + a1;
      }
      #pragma unroll
      for (int r = 0; r < RPB; ++r) red[r*512 + pa_ks*32 + pa_b] = part[r];
      __syncthreads();
      {
        int r = tid >> 5, b2 = tid & 31;
        const float* rp = &red[r*512 + b2];
        float s = 0.f;
        #pragma unroll
        for (int k2 = 0; k2 < 16; ++k2) s += rp[k2*32];
        if (na < H) qg[b2*H + na] = s + bqa;
        else        ghg[(size_t)b2*4*H + (na - H)] = s;
      }
      if (tid < 128){
        int r = 16 + (tid >> 5), b2 = tid & 31;
        const float* rp = &red[r*512 + b2];
        float s = 0.f;
        #pragma unroll
        for (int k2 = 0; k2 < 16; ++k2) s += rp[k2*32];
        if (nb < H) qg[b2*H + nb] = s + bqb;
        else        ghg[(size_t)b2*4*H + (nb - H)] = s;
      }
    }
    if (t == 0){
      gbar_full(bar, 1);
      if (tid == 0){
        my_cnt = __hip_atomic_load(&bar[832 + my_xcd*16], __ATOMIC_RELAXED, __HIP_MEMORY_SCOPE_AGENT);
        uint n = 0;
        #pragma unroll
        for (int g = 0; g < 8; ++g)
          n += (__hip_atomic_load(&bar[832 + g*16], __ATOMIC_RELAXED, __HIP_MEMORY_SCOPE_AGENT) != 0u) ? 1u : 0u;
        nx = n;
      }
    } else {
      gbar_x(bar, 2*t + 1, my_xcd, my_cnt, nx, lb); lb++;
    }

    // ================= PB =================
    {
      // q slice (16 floats, per lane) + gh, one wait; Gx issued right after
      float4 q4[4]; float ghv;
      ld_qgh_sc(qg + pb_b*H + lane*16, ghg + (size_t)pb_b*4*H + gn, q4, &ghv);
      float gxv = GxF[((size_t)t*B + pb_b)*4*H + gn];
      float qarr[16];
      *(float4*)&qarr[0] = q4[0]; *(float4*)&qarr[4]  = q4[1];
      *(float4*)&qarr[8] = q4[2]; *(float4*)&qarr[12] = q4[3];

      // scores: 8 waves over 41 s
      for (int s = wv; s < S; s += 8) {
        const ushort* kr = keys16 + ((size_t)pb_b*S + s)*H + lane*16;
        uint4 k0 = *(const uint4*)kr;
        uint4 k1 = *(const uint4*)(kr + 8);
        float part = 0.f;
        #define SC2(u, e) { h2v hh = bc2(u); \
          part += fast_tanh(qarr[e]   + (float)hh.x) * vreg[e]; \
          part += fast_tanh(qarr[e+1] + (float)hh.y) * vreg[e+1]; }
        SC2(k0.x,0) SC2(k0.y,2) SC2(k0.z,4) SC2(k0.w,6)
        SC2(k1.x,8) SC2(k1.y,10) SC2(k1.z,12) SC2(k1.w,14)
        #undef SC2
        #pragma unroll
        for (int off = 32; off > 0; off >>= 1) part += __shfl_xor(part, off);
        if (lane == 0) sc_sh[s] = part + bV0;
      }
      __syncthreads();
      if (tid < 64) {
        float val = (tid < S) ? sc_sh[tid] : -1e30f;
        float m = val;
        #pragma unroll
        for (int off = 32; off > 0; off >>= 1) m = fmaxf(m, __shfl_xor(m, off));
        float e = (tid < S) ? __expf(val - m) : 0.f;
        float ssum = e;
        #pragma unroll
        for (int off = 32; off > 0; off >>= 1) ssum += __shfl_xor(ssum, off);
        if (tid < S) {
          float w = e / ssum;
          sc_sh[tid] = w;
          if (pb_mc == 0) st_sc_f32(&attn_out[((size_t)pb_b*T + t)*S + tid], w);
        }
      }
      __syncthreads();
      {
        float acc = gxv + ghv;
        const ushort* ep = &ew_lds[tid*42];
        #pragma unroll
        for (int s = 0; s < S; ++s)
          acc = fmaf(sc_sh[s], h2f(ep[s]), acc);
        ga[tid] = acc;
      }
      __syncthreads();
      if (tid < 128) {
        float ig = fast_sigmoid(ga[tid]);
        float fg = fast_sigmoid(ga[128+tid]);
        float gg = fast_tanh   (ga[256+tid]);
        float og = fast_sigmoid(ga[384+tid]);
        creg = fg*creg + ig*gg;
        float hn = og * fast_tanh(creg);
        int m = pb_mc*128 + tid;
        h16[pb_b*H + m] = f2h(hn);
        st_sc_f32(&hhist[((size_t)pb_b*T + t)*H + m], hn);
        if (t == T-1) { hf[pb_b*H + m] = hn; cf[pb_b*H + m] = creg; }
      }
    }
    if (t < T-1) { gbar_x(bar, 2*t + 2, my_xcd, my_cnt, nx, lb); lb++; }
  }
}

// ---------------- log_softmax in-place over rows of 16384 ----------------
__global__ __launch_bounds__(256) void k_logsm(float* __restrict__ p_all)
{
  float* p = p_all + (size_t)blockIdx.x * V;
  const int tid = threadIdx.x;
  const int lane = tid & 63, wave = tid >> 6;
  __shared__ float red[4];
  float4 v[16];
  float m = -1e30f;
  #pragma unroll
  for (int j=0;j<16;j++){
    v[j] = *(const float4*)(p + 4*(tid + 256*j));
    m = fmaxf(m, fmaxf(fmaxf(v[j].x, v[j].y), fmaxf(v[j].z, v[j].w)));
  }
  #pragma unroll
  for (int off=32; off>0; off>>=1) m = fmaxf(m, __shfl_xor(m, off));
  if (lane==0) red[wave] = m;
  __syncthreads();
  m = fmaxf(fmaxf(red[0], red[1]), fmaxf(red[2], red[3]));
  float ssum = 0.f;
  #pragma unroll
  for (int j=0;j<16;j++){
    ssum += __expf(v[j].x - m) + __expf(v[j].y - m) + __expf(v[j].z - m) + __expf(v[j].w - m);
  }
  #pragma unroll
  for (int off=32; off>0; off>>=1) ssum += __shfl_xor(ssum, off);
  __syncthreads();
  if (lane==0) red[wave] = ssum;
  __syncthreads();
  float lse = m + __logf(red[0] + red[1] + red[2] + red[3]);
  #pragma unroll
  for (int j=0;j<16;j++){
    float4 o; o.x = v[j].x - lse; o.y = v[j].y - lse; o.z = v[j].z - lse; o.w = v[j].w - lse;
    *(float4*)(p + 4*(tid + 256*j)) = o;
  }
}

extern "C" void kernel_launch(void* const* d_in, const int* in_sizes, int n_in,
                              void* d_out, int out_size, void* d_ws, size_t ws_size,
                              hipStream_t stream) {
  const float* enc   = (const float*)d_in[0];
  const float* ehid  = (const float*)d_in[1];
  const int*   tgt   = (const int*)  d_in[2];
  const float* emb   = (const float*)d_in[3];
  const float* Wq    = (const float*)d_in[4];
  const float* bq    = (const float*)d_in[5];
  const float* Wk    = (const float*)d_in[6];
  const float* bk    = (const float*)d_in[7];
  const float* Vw    = (const float*)d_in[8];
  const float* bV    = (const float*)d_in[9];
  const float* Wih   = (const float*)d_in[10];
  const float* Whh   = (const float*)d_in[11];
  const float* bih   = (const float*)d_in[12];
  const float* bhh   = (const float*)d_in[13];
  const float* Wout  = (const float*)d_in[14];
  const float* bout  = (const float*)d_in[15];

  float* out  = (float*)d_out;
  float* dec  = out;                          // [1312][16384]
  float* hf   = out + (size_t)B*T*V;
  float* cf   = hf + BH;
  float* attn = cf + BH;

  // scratch inside dec (all dead before the logits GEMM rewrites dec)
  float*  Xall   = dec;                       //  1,343,488 f32
  float*  keysF  = dec +  1343488;            //  1,343,488 f32
  float*  GxF    = dec +  2686976;            //  5,373,952 f32
  float*  encWF  = dec +  8060928;            //  5,373,952 f32
  ushort* keys16 = (ushort*)(dec + 13434880); //  671,744 f32-slots
  ushort* encW16 = (ushort*)(dec + 14106624); //  2,686,976 f32-slots
  ushort* Wc16   = (ushort*)(dec + 16793600); //  2,621,440 f32-slots -> ends 19,415,040

  float* ws = (float*)d_ws;
  float*  hhist = ws;                          // 1,343,488 f32
  float*  bsum  = ws + 1343488;                // 4,096
  ushort* h16   = (ushort*)(ws + 1347584);     // 16,384 f32-slots
  float*  qg    = ws + 1363968;                // 32,768
  float*  ghg   = ws + 1396736;                // 131,072
  uint*   bar   = (uint*)(ws + 1527808);       // 1,024 uints

  k_init<<<BH/256, 256, 0, stream>>>(ehid, h16, bar);
  k_bsum<<<(4*H)/256, 256, 0, stream>>>(bih, bhh, bsum);
  k_gather<<<T*B, 256, 0, stream>>>(emb, tgt, Xall);

  // keys = enc @ Wk^T + bk
  { dim3 g(H/128, 11);     k_bgemm<<<g, 256, 0, stream>>>(enc,  Wk,  bk,     keysF, B*S, H,   H,   0); }
  // Gx = Xall @ Wih[:, :H]^T + (bih+bhh)
  { dim3 g((4*H)/128, 11); k_bgemm<<<g, 256, 0, stream>>>(Xall, Wih, bsum,   GxF,   T*B, 4*H, 2*H, 0); }
  // encW = enc @ Wih[:, H:]^T
  { dim3 g((4*H)/128, 11); k_bgemm<<<g, 256, 0, stream>>>(enc,  Wih, nullptr,encWF, B*S, 4*H, 2*H, H); }

  k_cvt16<<<(B*S*H/8 + 255)/256, 256, 0, stream>>>(keysF, keys16, B*S*H/8);
  k_cvt16<<<(B*S*4*H/8 + 255)/256, 256, 0, stream>>>(encWF, encW16, B*S*4*H/8);
  k_cvt16<<<(H*H/8 + 255)/256, 256, 0, stream>>>(Wq,  Wc16,             H*H/8);
  k_cvt16<<<(4*H*H/8 + 255)/256, 256, 0, stream>>>(Whh, Wc16 + (size_t)H*H, 4*H*H/8);

  // the 41-step recurrence: 256 persistent blocks, XCD-leader barriers
  {
    void* kargs[] = {
      (void*)&Wc16, (void*)&bq, (void*)&keys16, (void*)&Vw, (void*)&bV,
      (void*)&GxF, (void*)&encW16, (void*)&qg, (void*)&ghg,
      (void*)&h16, (void*)&hhist, (void*)&attn, (void*)&hf, (void*)&cf, (void*)&bar
    };
    hipLaunchCooperativeKernel((const void*)k_loop, dim3(NBLK), dim3(NTHR), kargs, 0, stream);
  }

  // logits = hhist @ Wout^T + bout -> dec rows (row = b*T+t), then log_softmax
  { dim3 g(V/128, 11);     k_bgemm<<<g, 256, 0, stream>>>(hhist, Wout, bout, dec, B*T, V, H, 0); }
  k_logsm<<<B*T, 256, 0, stream>>>(dec);
}